// Round 3
// baseline (91.016 us; speedup 1.0000x reference)
//
#include <hip/hip_runtime.h>

// PointSIFT: octant-wise nearest neighbor within radius + group.
// B=2, N=4096, C=64 fixed; xyz uniform in [0,1)^3, radius=0.25.
//
// Two-kernel design:
//   1. build_grid: counting-sort points into a 4x4x4 cell grid (cell width
//      0.25 = radius). Sorted float4 = (x,y,z, orig_idx bits) in d_ws.
//   2. select_gather: ONE WAVE PER QUERY, per-query candidate box [q-r,q+r].
//      Scoreboard = 8 u64 slots PER WAVE in LDS, updated with a predicated
//      fire-and-forget ds_min_u64 (only lanes with dist < judge issue it —
//      ~15% duty). Lexicographic u64 min of (key<<32|idx) == reference
//      first-min + original-index tie-break, scan-order-independent. Winners
//      are read straight from the wave's LDS slots (same-wave DS ordering is
//      in-order); gather fused in the epilogue.
//
// ROUND-3 BISECT: byte-identical to the round-0 kernel that passed at
// 90.9 us, EXCEPT select_gather's __launch_bounds__ 2nd arg 8 -> 4.
// (8 waves/EU caps the kernel at 64 VGPRs — below its live set -> scratch
// spills in the hot loop + epilogue. 4 waves/EU = 128-VGPR budget, still
// 16 waves/CU for latency hiding.) Rounds 1-2 failed at container level
// with a larger diff; this isolates infra-vs-kernel while testing the
// highest-value single change.
//
// Packed key: hi = float_bits(dist) - (float_bits(1e-10f)+1)
//   - dist <= 1e-10 (incl. self) wraps to huge -> loses to the seed
//   - dist >= judge never issues the atomic (strict-< exact)
//   - valid dists monotone; ties on key fall to min orig idx = ref tie-break
#define BB 2
#define NN 4096
#define CC 64
#define QPB 4               // queries per select block (one per wave)
#define TPQ 64              // threads per query = full wave
#define NT 256              // threads per select block

// flat output layout (all float32):
//   out0 grouped_xyz   [B,N,8,3]
//   out1 grouped_points[B,N,8,67]
//   out2 idx (as float)[B,N,8]
#define OUT0_OFF 0
#define OUT1_OFF (BB * NN * 8 * 3)               /* 196608 */
#define OUT2_OFF (OUT1_OFF + BB * NN * 8 * 67)   /* 4587520 */

// d_ws layout: sorted float4 [B*NN], then offsets int [B*65]
#define WS_SORTED_BYTES (BB * NN * 16)

__global__ __launch_bounds__(1024) void build_grid(
    const float* __restrict__ xyz, float4* __restrict__ sorted,
    int* __restrict__ offsets)
{
    __shared__ int hist[64];
    __shared__ int offs[65];
    const int b = blockIdx.x;
    const int tid = threadIdx.x;
    if (tid < 64) hist[tid] = 0;
    __syncthreads();
    const float* src = xyz + (size_t)b * NN * 3;
    #pragma unroll
    for (int p = tid; p < NN; p += 1024) {
        float x = src[p * 3 + 0], y = src[p * 3 + 1], z = src[p * 3 + 2];
        int cell = (((int)(x * 4.0f)) << 4) | (((int)(y * 4.0f)) << 2)
                 | ((int)(z * 4.0f));            // x in [0,1) -> cell in [0,64)
        atomicAdd(&hist[cell], 1);
    }
    __syncthreads();
    if (tid < 64) {                              // wave 0: shfl prefix scan
        int inc = hist[tid];
        #pragma unroll
        for (int d = 1; d < 64; d <<= 1) {
            int u = __shfl_up(inc, d, 64);
            if (tid >= d) inc += u;
        }
        offs[tid + 1] = inc;                     // inclusive -> offs[1..64]
        if (tid == 0) offs[0] = 0;
    }
    __syncthreads();
    if (tid < 65) offsets[b * 65 + tid] = offs[tid];
    if (tid < 64) hist[tid] = offs[tid];         // reuse as scatter cursors
    __syncthreads();
    float4* dst = sorted + (size_t)b * NN;
    #pragma unroll
    for (int p = tid; p < NN; p += 1024) {
        float x = src[p * 3 + 0], y = src[p * 3 + 1], z = src[p * 3 + 2];
        int cell = (((int)(x * 4.0f)) << 4) | (((int)(y * 4.0f)) << 2)
                 | ((int)(z * 4.0f));
        int pos = atomicAdd(&hist[cell], 1);     // order within cell arbitrary
        dst[pos] = make_float4(x, y, z, __uint_as_float((unsigned)p));
    }
}

__global__ __launch_bounds__(NT, 4) void select_gather(
    const float4* __restrict__ sorted, const int* __restrict__ offsets,
    const float* __restrict__ xyz, const float* __restrict__ points,
    const float* __restrict__ radius_p, float* __restrict__ out)
{
    __shared__ int s_off[65];
    __shared__ unsigned long long s_sb[QPB * 8];  // 8 u64 slots per wave

    const int tid = threadIdx.x;
    const int blk = blockIdx.x;
    const int b = blk >> 10;                     // 1024 blocks per batch
    const int qslot = (blk & 1023) * QPB;        // sorted-array slot base
    const float4* sb = sorted + (size_t)b * NN;

    if (tid < 65) s_off[tid] = offsets[b * 65 + tid];

    const float r = radius_p[0];
    const float judge = __fmul_rn(r, r);
    const unsigned OFFC = __float_as_uint(1e-10f) + 1u;   // wrap offset
    const unsigned seedkey = __float_as_uint(judge) - OFFC;

    // own query: one WAVE per query (box is wave-uniform -> no divergence)
    const int g = tid >> 6;                      // query group = wave id 0..3
    const float4 q = sb[qslot + g];
    const unsigned n = __float_as_uint(q.w);     // original index
    const float qx = q.x, qy = q.y, qz = q.z;
    const int sub = tid & 63;

    // seed this wave's 8 slots (same-wave DS ops are in-order: seeds land
    // before any later atomic from this wave; no other wave touches them)
    const unsigned long long seed64 = ((unsigned long long)seedkey << 32) | n;
    if (sub < 8) s_sb[g * 8 + sub] = seed64;

    // per-query candidate box: cells overlapping [q-r, q+r] (<= 3 per axis)
    const int lx = max(0, (int)((qx - r) * 4.0f));
    const int hx = min(3, (int)((qx + r) * 4.0f));
    const int ly = max(0, (int)((qy - r) * 4.0f));
    const int hy = min(3, (int)((qy + r) * 4.0f));
    const int lz = max(0, (int)((qz - r) * 4.0f));
    const int hz = min(3, (int)((qz + r) * 4.0f));

    __syncthreads();                             // s_off ready

    for (int cx = lx; cx <= hx; ++cx) {
        for (int cy = ly; cy <= hy; ++cy) {
            const int cb = (cx << 4) | (cy << 2);
            const int s = s_off[cb + lz];
            const int e = s_off[cb + hz + 1];    // cz-contiguous run
            #pragma unroll 2
            for (int p = s + sub; p < e; p += TPQ) {
                float4 c = sb[p];
                // diff = candidate - query, fp32, no contraction (match ref)
                float dx = __fsub_rn(c.x, qx);
                float dy = __fsub_rn(c.y, qy);
                float dz = __fsub_rn(c.z, qz);
                float dist = __fadd_rn(__fadd_rn(__fmul_rn(dx, dx),
                                                 __fmul_rn(dy, dy)),
                                       __fmul_rn(dz, dz));
                // only ~15% of box candidates are inside the ball: everyone
                // else skips the scoreboard entirely (predicated atomic).
                if (dist < judge) {
                    // monotone packed key; dist<=1e-10 (incl. self) wraps to
                    // a huge key and loses to the seed automatically
                    unsigned ikey = __float_as_uint(dist) - OFFC;
                    // octant code = trunc(d+1.0f) dot [4,2,1]; coords in
                    // [0,1) -> d+1.0f in (0,2) -> each bit already 0/1
                    int code = (((int)__fadd_rn(dx, 1.0f)) * 4 +
                                ((int)__fadd_rn(dy, 1.0f)) * 2 +
                                ((int)__fadd_rn(dz, 1.0f)));
                    atomicMin(&s_sb[g * 8 + code],
                              ((unsigned long long)ikey << 32) |
                              (unsigned long long)__float_as_uint(c.w));
                }
            }
        }
    }

    // read winners straight from the wave's slots (in-order after atomics;
    // broadcast reads, no butterfly needed)
    unsigned idx8[8];
    #pragma unroll
    for (int o = 0; o < 8; ++o)
        idx8[o] = (unsigned)(s_sb[g * 8 + o] & 0xFFFFFFFFull);

    // ---- fused epilogue: this wave writes its query's entire output ----
    const size_t tb = ((size_t)b * NN + n) * 8;
    if (sub < 8)
        out[OUT2_OFF + tb + sub] = (float)idx8[sub];

    const float* xb = xyz + (size_t)b * NN * 3;
    const float* pb = points + (size_t)b * NN * CC;
    // per-lane query component for the xyz-diff lanes (0..2)
    const float qc = (sub == 0) ? qx : ((sub == 1) ? qy : qz);
    #pragma unroll
    for (int o = 0; o < 8; ++o) {
        const int i = (int)idx8[o];                          // wave-uniform
        const size_t t = tb + o;
        float v;
        if (sub < 3) v = __fsub_rn(xb[i * 3 + sub], qc);
        else         v = pb[(size_t)i * CC + (sub - 3)];
        __builtin_nontemporal_store(v, &out[OUT1_OFF + t * 67 + sub]);
        if (sub >= 61)                                       // ch 64..66
            __builtin_nontemporal_store(pb[(size_t)i * CC + sub],
                                        &out[OUT1_OFF + t * 67 + (sub + 3)]);
        if (sub < 3)
            __builtin_nontemporal_store(v, &out[OUT0_OFF + t * 3 + sub]);
    }
}

extern "C" void kernel_launch(void* const* d_in, const int* in_sizes, int n_in,
                              void* d_out, int out_size, void* d_ws, size_t ws_size,
                              hipStream_t stream) {
    const float* xyz    = (const float*)d_in[0];
    const float* points = (const float*)d_in[1];
    const float* radius = (const float*)d_in[2];
    float* out = (float*)d_out;
    float4* ws_sorted = (float4*)d_ws;
    int* ws_offsets = (int*)((char*)d_ws + WS_SORTED_BYTES);

    // 1: counting-sort into 4x4x4 cells (one block per batch)
    hipLaunchKernelGGL(build_grid, dim3(BB), dim3(1024), 0, stream,
                       xyz, ws_sorted, ws_offsets);
    // 2: per-query-wave pruned octant select + fused gather (2048 blocks)
    hipLaunchKernelGGL(select_gather,
                       dim3(BB * (NN / QPB)), dim3(NT), 0, stream,
                       ws_sorted, ws_offsets, xyz, points, radius, out);
}